// Round 5
// baseline (190.672 us; speedup 1.0000x reference)
//
#include <hip/hip_runtime.h>
#include <cstdint>

// ViT patch embedding, two-stage.
//   prep_all:  image-linear patchify+cvt -> bf16 A, W -> bf16 Wb, cls -> out.
//   vit_gemm4: R5 restructure. R4 post-mortem: depth-3 = null => not
//              load-latency-bound; arithmetic says LDS pipe ~58% + 2-phase
//              stage/barrier chain is the ceiling (640 TF ~ m233's 607-682).
//              Changes: 256x256 tile, 512 thr, 8 waves, 8x4 reg blocking
//              (-25% ds_read per MFMA); global_load_lds staging (no wave
//              ds_writes, no staging VGPRs); raw s_barrier + counted
//              vmcnt(8) so prefetch spans 2 steps (never vmcnt(0) mid-loop).
//              Swizzle: linear LDS dest + inverse-XOR global source + XOR
//              read (rule #21, same involution as verified R0 kernel).
//              Grid 294 blocks (1/CU at 128KB LDS), bijective XCD swizzle.

#define PGRID 14
#define PSZ   16
#define CHN   3
#define IMGW  224
#define KDIM  768
#define NDIM  768
#define NPATCH 196

typedef short bf16x8 __attribute__((ext_vector_type(8)));
typedef short short8v __attribute__((ext_vector_type(8)));
typedef float f32x4  __attribute__((ext_vector_type(4)));

typedef __attribute__((address_space(1))) void GV;
typedef __attribute__((address_space(3))) void LV;

__device__ __forceinline__ void gload_lds16(const void* g, void* l) {
    __builtin_amdgcn_global_load_lds((GV*)g, (LV*)l, 16, 0, 0);
}

__device__ __forceinline__ short bf16rne(float f) {
    uint32_t u = __builtin_bit_cast(uint32_t, f);
    u += 0x7FFFu + ((u >> 16) & 1u);
    return (short)(u >> 16);
}

__device__ __forceinline__ short8v cvt8(float4 v0, float4 v1) {
    short8v s;
    s[0] = bf16rne(v0.x); s[1] = bf16rne(v0.y); s[2] = bf16rne(v0.z); s[3] = bf16rne(v0.w);
    s[4] = bf16rne(v1.x); s[5] = bf16rne(v1.y); s[6] = bf16rne(v1.z); s[7] = bf16rne(v1.w);
    return s;
}

// ---------------- prep: patchify + W convert + cls fill, image-linear ----------------
__global__ __launch_bounds__(256) void prep_all(
    const float* __restrict__ img, const float* __restrict__ Wl,
    const float* __restrict__ cls, short* __restrict__ A,
    short* __restrict__ Wb, float* __restrict__ out, int n_img)
{
    const int IMG8 = n_img * (CHN * IMGW * IMGW / 8);   // n*18816
    const int W8   = KDIM * NDIM / 8;                   // 73728
    int t = blockIdx.x * 256 + threadIdx.x;

    if (t < IMG8) {
        int w8    = t % (IMGW / 8);        // 0..27
        int rest  = t / (IMGW / 8);
        int h     = rest % IMGW;
        int rest2 = rest / IMGW;
        int c     = rest2 % CHN;
        int im    = rest2 / CHN;

        float4 v0 = *(const float4*)(img + (long)t * 8);
        float4 v1 = *(const float4*)(img + (long)t * 8 + 4);

        int Pi = h >> 4;
        int ph = h & 15;
        int Pj = w8 >> 1;
        int pw = (w8 & 1) * 8;
        int m  = im * NPATCH + Pi * PGRID + Pj;
        int k  = (c << 8) + (ph << 4) + pw;
        *(short8v*)(A + (long)m * KDIM + k) = cvt8(v0, v1);
    } else if (t < IMG8 + W8) {
        int u = t - IMG8;
        float4 v0 = *(const float4*)(Wl + (long)u * 8);
        float4 v1 = *(const float4*)(Wl + (long)u * 8 + 4);
        *(short8v*)(Wb + (long)u * 8) = cvt8(v0, v1);
    } else {
        int u = t - IMG8 - W8;
        if (u < n_img * (NDIM / 8)) {
            int im = u / (NDIM / 8);
            int k8 = u - im * (NDIM / 8);
            float4 v0 = *(const float4*)(cls + k8 * 8);
            float4 v1 = *(const float4*)(cls + k8 * 8 + 4);
            float* dst = out + (long)im * 197 * NDIM + k8 * 8;
            *(float4*)dst = v0;
            *(float4*)(dst + 4) = v1;
        }
    }
}

// ---------------- main GEMM: bf16 A[M][768] @ Wb[768][768]^T + bias ----------------
// 256x256 tile, 512 threads, K-tile 64, dbuf LDS via global_load_lds.
__global__ __launch_bounds__(512) void vit_gemm4(
    const short* __restrict__ A, const short* __restrict__ B,
    const float* __restrict__ bias, float* __restrict__ out,
    int M, int mgroups)
{
    // bijective XCD swizzle (m204): consecutive wgid land on one XCD,
    // so the 3 n-blocks sharing an A-panel co-locate.
    const int nwg = mgroups * 3;
    const int q = nwg >> 3, r = nwg & 7;
    const int xcd = blockIdx.x & 7;
    const int idx = blockIdx.x >> 3;
    const int wgid = (xcd < r ? xcd * (q + 1) : r * (q + 1) + (xcd - r) * q) + idx;
    const int g = wgid / 3;
    const int j = wgid - g * 3;
    const int m0 = g * 256;
    const int n0 = j * 256;

    // LDS: 2 buffers x (A 256x64 + B 256x64) bf16 = 2 x 64 KB = 128 KB.
    // Within buffer: A at [0..16384) shorts, B at [16384..32768).
    // Layout: slot s (row = s>>3, phys chunk = s&7) at s*8 shorts; phys
    // chunk p of row r holds logical k-chunk p ^ (r&7) (XOR swizzle,
    // applied on the GLOBAL source address — LDS dest stays linear).
    __shared__ short LDS[2][32768];

    const int tid  = threadIdx.x;          // 0..511
    const int wid  = tid >> 6;
    const int lane = tid & 63;
    const int wr = wid >> 2;               // 0..1  -> m-offset
    const int wc = wid & 3;                // 0..3  -> n-offset
    const int wm = wr * 128;
    const int wn = wc * 64;
    const int wq = lane >> 4;
    const int lr = lane & 15;
    const int blk0 = ((wq)     ^ (lr & 7)) * 8;
    const int blk1 = ((wq + 4) ^ (lr & 7)) * 8;

    // staging coords: loads l=0..3 cover slots l*512+tid; row = l*64+srow
    const int srow = tid >> 3;             // 0..63
    const int sk   = (tid & 7) ^ (srow & 7);
    const long abase = (long)(m0 + srow) * KDIM + sk * 8;
    const long bbase = (long)(n0 + srow) * KDIM + sk * 8;
    const int  lslot = tid * 8;            // this thread's slot-0 LDS offset (shorts)

    f32x4 acc[8][4] = {};

#define STAGE(CUR, KK)                                                       \
    {                                                                        \
        _Pragma("unroll")                                                    \
        for (int l = 0; l < 4; ++l) {                                        \
            gload_lds16(A + abase + (long)l * 64 * KDIM + (KK),              \
                        &LDS[CUR][l * 4096 + lslot]);                        \
            gload_lds16(B + bbase + (long)l * 64 * KDIM + (KK),              \
                        &LDS[CUR][16384 + l * 4096 + lslot]);                \
        }                                                                    \
    }

#define COMPUTE(CUR)                                                         \
    {                                                                        \
        _Pragma("unroll")                                                    \
        for (int ks = 0; ks < 2; ++ks) {                                     \
            const int blk = ks ? blk1 : blk0;                                \
            bf16x8 a[8], b[4];                                               \
            _Pragma("unroll")                                                \
            for (int i = 0; i < 8; ++i)                                      \
                a[i] = *(const bf16x8*)(&LDS[CUR][(wm + i * 16 + lr) * 64 + blk]); \
            _Pragma("unroll")                                                \
            for (int jm = 0; jm < 4; ++jm)                                   \
                b[jm] = *(const bf16x8*)(&LDS[CUR][16384 + (wn + jm * 16 + lr) * 64 + blk]); \
            _Pragma("unroll")                                                \
            for (int i = 0; i < 8; ++i)                                      \
                _Pragma("unroll")                                            \
                for (int jm = 0; jm < 4; ++jm)                               \
                    acc[i][jm] = __builtin_amdgcn_mfma_f32_16x16x32_bf16(    \
                        a[i], b[jm], acc[i][jm], 0, 0, 0);                   \
        }                                                                    \
    }

    // prologue: tiles 0,1 in flight (16 loads/thread total)
    STAGE(0, 0)
    STAGE(1, 64)

    // 12 K-steps. Step t: wait own prefetch of tile t (vmcnt: 16 outstanding
    // -> 8, FIFO => tile t landed), barrier (all waves waited), compute,
    // barrier (all reads of buf done), issue tile t+2 into the same buffer.
    for (int t = 0; t < 12; ++t) {
        const int cur = t & 1;
        if (t == 11) { asm volatile("s_waitcnt vmcnt(0)" ::: "memory"); }
        else         { asm volatile("s_waitcnt vmcnt(8)" ::: "memory"); }
        __builtin_amdgcn_s_barrier();
        asm volatile("" ::: "memory");
        COMPUTE(cur)
        asm volatile("" ::: "memory");
        __builtin_amdgcn_s_barrier();
        asm volatile("" ::: "memory");
        if (t < 10) STAGE(cur, (t + 2) * 64)
    }

#undef STAGE
#undef COMPUTE

    float bv[4];
    #pragma unroll
    for (int jm = 0; jm < 4; ++jm) bv[jm] = bias[n0 + wn + jm * 16 + lr];

    #pragma unroll
    for (int i = 0; i < 8; ++i) {
        #pragma unroll
        for (int rr = 0; rr < 4; ++rr) {
            int gm = m0 + wm + i * 16 + wq * 4 + rr;
            if (gm < M) {
                int im = gm / NPATCH;
                int p  = gm - im * NPATCH;
                long orow = ((long)im * 197 + 1 + p) * (long)NDIM;
                #pragma unroll
                for (int jm = 0; jm < 4; ++jm)
                    out[orow + n0 + wn + jm * 16 + lr] = acc[i][jm][rr] + bv[jm];
            }
        }
    }
}

// ---------------- fallback (no ws needed) ----------------
#define LDSTR 40
__global__ __launch_bounds__(256) void vit_gemm_fb(
    const float* __restrict__ img, const float* __restrict__ Wl,
    const float* __restrict__ bias, float* __restrict__ out, int n_img)
{
    const int M = n_img * NPATCH;
    __shared__ short As[128 * LDSTR];
    __shared__ short Bs[128 * LDSTR];
    const int tid = threadIdx.x;
    const int m0 = blockIdx.y * 128;
    const int n0 = blockIdx.x * 128;
    const int col4  = tid & 7;
    const int rbase = tid >> 3;
    long arow[4];
    for (int rr = 0; rr < 4; ++rr) {
        int m = m0 + rbase + rr * 32;
        int mm = (m < M) ? m : (M - 1);
        int im = mm / NPATCH;
        int p  = mm % NPATCH;
        int Pi = p / PGRID;
        int Pj = p % PGRID;
        arow[rr] = ((long)(im * CHN) * IMGW + Pi * PSZ) * IMGW + Pj * PSZ;
    }
    const int lane = tid & 63;
    const int wave = tid >> 6;
    const int wm = (wave & 1) * 64;
    const int wn = (wave >> 1) * 64;
    const int wq = lane >> 4;
    const int lr = lane & 15;
    f32x4 acc[4][4] = {};
    for (int k0 = 0; k0 < KDIM; k0 += 32) {
        {
            int k  = k0 + col4 * 4;
            int c  = k >> 8;
            int ph = (k >> 4) & 15;
            int pw = k & 15;
            long koff = (long)(c * IMGW + ph) * IMGW + pw;
            #pragma unroll
            for (int rr = 0; rr < 4; ++rr) {
                const float4 v = *(const float4*)(img + arow[rr] + koff);
                int row = rbase + rr * 32;
                short4 s;
                s.x = bf16rne(v.x); s.y = bf16rne(v.y);
                s.z = bf16rne(v.z); s.w = bf16rne(v.w);
                *(short4*)(&As[row * LDSTR + col4 * 4]) = s;
            }
        }
        {
            int k = k0 + col4 * 4;
            #pragma unroll
            for (int rr = 0; rr < 4; ++rr) {
                int nrow = rbase + rr * 32;
                const float4 v = *(const float4*)(Wl + (long)(n0 + nrow) * KDIM + k);
                short4 s;
                s.x = bf16rne(v.x); s.y = bf16rne(v.y);
                s.z = bf16rne(v.z); s.w = bf16rne(v.w);
                *(short4*)(&Bs[nrow * LDSTR + col4 * 4]) = s;
            }
        }
        __syncthreads();
        bf16x8 a[4], b[4];
        #pragma unroll
        for (int i = 0; i < 4; ++i)
            a[i] = *(const bf16x8*)(&As[(wm + i * 16 + lr) * LDSTR + wq * 8]);
        #pragma unroll
        for (int i = 0; i < 4; ++i)
            b[i] = *(const bf16x8*)(&Bs[(wn + i * 16 + lr) * LDSTR + wq * 8]);
        #pragma unroll
        for (int i = 0; i < 4; ++i)
            #pragma unroll
            for (int j = 0; j < 4; ++j)
                acc[i][j] = __builtin_amdgcn_mfma_f32_16x16x32_bf16(a[i], b[j], acc[i][j], 0, 0, 0);
        __syncthreads();
    }
    float bv[4];
    #pragma unroll
    for (int j = 0; j < 4; ++j) bv[j] = bias[n0 + wn + j * 16 + lr];
    #pragma unroll
    for (int i = 0; i < 4; ++i) {
        #pragma unroll
        for (int r = 0; r < 4; ++r) {
            int gm = m0 + wm + i * 16 + wq * 4 + r;
            if (gm < M) {
                int im = gm / NPATCH;
                int p  = gm % NPATCH;
                long orow = ((long)im * 197 + 1 + p) * (long)NDIM;
                #pragma unroll
                for (int j = 0; j < 4; ++j)
                    out[orow + n0 + wn + j * 16 + lr] = acc[i][j][r] + bv[j];
            }
        }
    }
}

__global__ __launch_bounds__(256) void cls_fill(
    const float* __restrict__ cls, float* __restrict__ out, int n_img)
{
    int i = blockIdx.x * 256 + threadIdx.x;
    if (i < n_img * NDIM) {
        int im = i / NDIM;
        int n  = i - im * NDIM;
        out[(long)im * 197 * NDIM + n] = cls[n];
    }
}

extern "C" void kernel_launch(void* const* d_in, const int* in_sizes, int n_in,
                              void* d_out, int out_size, void* d_ws, size_t ws_size,
                              hipStream_t stream) {
    const float* img  = (const float*)d_in[0];
    const float* Wl   = (const float*)d_in[1];
    const float* bias = (const float*)d_in[2];
    const float* cls  = (const float*)d_in[3];
    float* out = (float*)d_out;

    int n_img = in_sizes[0] / (CHN * IMGW * IMGW);
    int M = n_img * NPATCH;
    int mgroups = (M + 255) / 256;
    long Mpad = (long)mgroups * 256;

    size_t need = (size_t)(Mpad * KDIM + (long)KDIM * NDIM) * sizeof(short);
    if (ws_size >= need) {
        short* A_ws = (short*)d_ws;
        short* Wb   = A_ws + Mpad * KDIM;

        int total8 = n_img * (CHN * IMGW * IMGW / 8)
                   + KDIM * NDIM / 8
                   + n_img * (NDIM / 8);
        prep_all<<<(total8 + 255) / 256, 256, 0, stream>>>(img, Wl, cls, A_ws, Wb, out, n_img);

        int nwg = mgroups * 3;
        vit_gemm4<<<nwg, 512, 0, stream>>>(A_ws, Wb, bias, out, M, mgroups);
    } else {
        dim3 grid(NDIM / 128, (M + 127) / 128);
        vit_gemm_fb<<<grid, 256, 0, stream>>>(img, Wl, bias, out, n_img);
        int cls_elems = n_img * NDIM;
        cls_fill<<<(cls_elems + 255) / 256, 256, 0, stream>>>(cls, out, n_img);
    }
}

// Round 6
// 174.724 us; speedup vs baseline: 1.0913x; 1.0913x over previous
//
#include <hip/hip_runtime.h>
#include <cstdint>

// ViT patch embedding, two-stage.
//   prep_all:  image-linear patchify+cvt -> bf16 A, W -> bf16 Wb, cls -> out.
//   vit_gemm5: R6 = R3 geometry + R5 staging, unbundled.
//              R5 post-mortem: 256^2 tile died on grid quantization (294
//              blocks @ 1/CU -> ~2 half-idle rounds) and zero co-resident
//              overlap; the DMA+counted-vmcnt schedule itself was never
//              isolated. Here: 128^2 tile, 1176 blocks (4.6/CU), 64 KB LDS
//              -> 2 blocks/CU co-resident (R3's verified balance), staged
//              via global_load_lds (no wave ds_writes, no staging VGPRs),
//              raw s_barrier + vmcnt(8) so tile t+2's loads stay in flight
//              across 2 full steps (never vmcnt(0) mid-loop).
//              Swizzle: linear LDS dest + inverse-XOR global source + XOR
//              read — same verified involution as R0/R3 (0 conflicts).

#define PGRID 14
#define PSZ   16
#define CHN   3
#define IMGW  224
#define KDIM  768
#define NDIM  768
#define NPATCH 196

typedef short bf16x8 __attribute__((ext_vector_type(8)));
typedef short short8v __attribute__((ext_vector_type(8)));
typedef float f32x4  __attribute__((ext_vector_type(4)));

typedef __attribute__((address_space(1))) void GV;
typedef __attribute__((address_space(3))) void LV;

__device__ __forceinline__ void gload_lds16(const void* g, void* l) {
    __builtin_amdgcn_global_load_lds((GV*)g, (LV*)l, 16, 0, 0);
}

__device__ __forceinline__ short bf16rne(float f) {
    uint32_t u = __builtin_bit_cast(uint32_t, f);
    u += 0x7FFFu + ((u >> 16) & 1u);
    return (short)(u >> 16);
}

__device__ __forceinline__ short8v cvt8(float4 v0, float4 v1) {
    short8v s;
    s[0] = bf16rne(v0.x); s[1] = bf16rne(v0.y); s[2] = bf16rne(v0.z); s[3] = bf16rne(v0.w);
    s[4] = bf16rne(v1.x); s[5] = bf16rne(v1.y); s[6] = bf16rne(v1.z); s[7] = bf16rne(v1.w);
    return s;
}

// ---------------- prep: patchify + W convert + cls fill, image-linear ----------------
__global__ __launch_bounds__(256) void prep_all(
    const float* __restrict__ img, const float* __restrict__ Wl,
    const float* __restrict__ cls, short* __restrict__ A,
    short* __restrict__ Wb, float* __restrict__ out, int n_img)
{
    const int IMG8 = n_img * (CHN * IMGW * IMGW / 8);   // n*18816
    const int W8   = KDIM * NDIM / 8;                   // 73728
    int t = blockIdx.x * 256 + threadIdx.x;

    if (t < IMG8) {
        int w8    = t % (IMGW / 8);        // 0..27
        int rest  = t / (IMGW / 8);
        int h     = rest % IMGW;
        int rest2 = rest / IMGW;
        int c     = rest2 % CHN;
        int im    = rest2 / CHN;

        float4 v0 = *(const float4*)(img + (long)t * 8);
        float4 v1 = *(const float4*)(img + (long)t * 8 + 4);

        int Pi = h >> 4;
        int ph = h & 15;
        int Pj = w8 >> 1;
        int pw = (w8 & 1) * 8;
        int m  = im * NPATCH + Pi * PGRID + Pj;
        int k  = (c << 8) + (ph << 4) + pw;
        *(short8v*)(A + (long)m * KDIM + k) = cvt8(v0, v1);
    } else if (t < IMG8 + W8) {
        int u = t - IMG8;
        float4 v0 = *(const float4*)(Wl + (long)u * 8);
        float4 v1 = *(const float4*)(Wl + (long)u * 8 + 4);
        *(short8v*)(Wb + (long)u * 8) = cvt8(v0, v1);
    } else {
        int u = t - IMG8 - W8;
        if (u < n_img * (NDIM / 8)) {
            int im = u / (NDIM / 8);
            int k8 = u - im * (NDIM / 8);
            float4 v0 = *(const float4*)(cls + k8 * 8);
            float4 v1 = *(const float4*)(cls + k8 * 8 + 4);
            float* dst = out + (long)im * 197 * NDIM + k8 * 8;
            *(float4*)dst = v0;
            *(float4*)(dst + 4) = v1;
        }
    }
}

// ---------------- main GEMM: bf16 A[M][768] @ Wb[768][768]^T + bias ----------------
// 128x128 tile, 256 threads, 4 waves (2x2, wave tile 64x64), K-step 64,
// dbuf LDS (2x32KB) via global_load_lds, counted vmcnt, raw s_barrier.
__global__ __launch_bounds__(256) void vit_gemm5(
    const short* __restrict__ A, const short* __restrict__ B,
    const float* __restrict__ bias, float* __restrict__ out,
    int M, int mgroups)
{
    // XCD-aware decode (verified R0): 6 n-blocks of one m-group -> same XCD
    const int bid = blockIdx.x;
    const int xcd = bid & 7;
    const int s   = bid >> 3;
    const int gq  = s / 6;
    const int j   = s - gq * 6;
    const int g   = gq * 8 + xcd;          // m-group
    if (g >= mgroups) return;
    const int m0 = g * 128;
    const int n0 = j * 128;

    // LDS: 2 buffers x (A 128x64 + B 128x64) bf16 = 2 x 32 KB = 64 KB.
    // Per buffer: A at [0..8192) shorts, B at [8192..16384).
    // Slot b = l*256+tid at b*8 shorts; row = b>>3, phys chunk = b&7 holds
    // logical k-chunk (b&7)^(row&7) — XOR involution applied on the GLOBAL
    // source address; LDS dest stays linear (rule #21).
    __shared__ short LDS[2][16384];

    const int tid  = threadIdx.x;
    const int wave = tid >> 6;
    const int lane = tid & 63;

    const int srow = tid >> 3;             // 0..31
    const int sk   = (tid & 7) ^ (srow & 7);
    const long abase = (long)(m0 + srow) * KDIM + sk * 8;
    const long bbase = (long)(n0 + srow) * KDIM + sk * 8;
    const int  lslot = tid * 8;            // this thread's slot-0 LDS offset (shorts)

    // compute coords (identical to verified R3 kernel)
    const int wm = (wave & 1) * 64;
    const int wn = (wave >> 1) * 64;
    const int wq = lane >> 4;
    const int lr = lane & 15;
    const int blk0 = ((wq)     ^ (lr & 7)) * 8;
    const int blk1 = ((wq + 4) ^ (lr & 7)) * 8;

    f32x4 acc[4][4] = {};

#define STAGE(CUR, KK)                                                       \
    {                                                                        \
        _Pragma("unroll")                                                    \
        for (int l = 0; l < 4; ++l) {                                        \
            gload_lds16(A + abase + (long)l * 32 * KDIM + (KK),              \
                        &LDS[CUR][l * 2048 + lslot]);                        \
            gload_lds16(B + bbase + (long)l * 32 * KDIM + (KK),              \
                        &LDS[CUR][8192 + l * 2048 + lslot]);                 \
        }                                                                    \
    }

#define COMPUTE(CUR)                                                         \
    {                                                                        \
        _Pragma("unroll")                                                    \
        for (int ks = 0; ks < 2; ++ks) {                                     \
            const int blk = ks ? blk1 : blk0;                                \
            bf16x8 a[4], b[4];                                               \
            _Pragma("unroll")                                                \
            for (int i = 0; i < 4; ++i)                                      \
                a[i] = *(const bf16x8*)(&LDS[CUR][(wm + i * 16 + lr) * 64 + blk]); \
            _Pragma("unroll")                                                \
            for (int jm = 0; jm < 4; ++jm)                                   \
                b[jm] = *(const bf16x8*)(&LDS[CUR][8192 + (wn + jm * 16 + lr) * 64 + blk]); \
            _Pragma("unroll")                                                \
            for (int i = 0; i < 4; ++i)                                      \
                _Pragma("unroll")                                            \
                for (int jm = 0; jm < 4; ++jm)                               \
                    acc[i][jm] = __builtin_amdgcn_mfma_f32_16x16x32_bf16(    \
                        a[i], b[jm], acc[i][jm], 0, 0, 0);                   \
        }                                                                    \
    }

    // prologue: tiles 0,1 in flight (8 loads/thread each)
    STAGE(0, 0)
    STAGE(1, 64)

    // 12 K-steps. Step t: vmcnt(8) => this wave's tile-t loads landed
    // (FIFO: 16 outstanding -> 8); barrier => all waves' landed; compute;
    // barrier => all reads of buf done; issue tile t+2 into same buffer.
    for (int t = 0; t < 12; ++t) {
        const int cur = t & 1;
        if (t == 11) { asm volatile("s_waitcnt vmcnt(0)" ::: "memory"); }
        else         { asm volatile("s_waitcnt vmcnt(8)" ::: "memory"); }
        __builtin_amdgcn_s_barrier();
        asm volatile("" ::: "memory");
        COMPUTE(cur)
        asm volatile("" ::: "memory");
        __builtin_amdgcn_s_barrier();
        asm volatile("" ::: "memory");
        if (t < 10) STAGE(cur, (t + 2) * 64)
    }

#undef STAGE
#undef COMPUTE

    float bv[4];
    #pragma unroll
    for (int jm = 0; jm < 4; ++jm) bv[jm] = bias[n0 + wn + jm * 16 + lr];

    #pragma unroll
    for (int i = 0; i < 4; ++i) {
        #pragma unroll
        for (int r = 0; r < 4; ++r) {
            int gm = m0 + wm + i * 16 + wq * 4 + r;
            if (gm < M) {
                int im = gm / NPATCH;
                int p  = gm - im * NPATCH;
                long orow = ((long)im * 197 + 1 + p) * (long)NDIM;
                #pragma unroll
                for (int jm = 0; jm < 4; ++jm)
                    out[orow + n0 + wn + jm * 16 + lr] = acc[i][jm][r] + bv[jm];
            }
        }
    }
}

// ---------------- fallback (no ws needed) ----------------
#define LDSTR 40
__global__ __launch_bounds__(256) void vit_gemm_fb(
    const float* __restrict__ img, const float* __restrict__ Wl,
    const float* __restrict__ bias, float* __restrict__ out, int n_img)
{
    const int M = n_img * NPATCH;
    __shared__ short As[128 * LDSTR];
    __shared__ short Bs[128 * LDSTR];
    const int tid = threadIdx.x;
    const int m0 = blockIdx.y * 128;
    const int n0 = blockIdx.x * 128;
    const int col4  = tid & 7;
    const int rbase = tid >> 3;
    long arow[4];
    for (int rr = 0; rr < 4; ++rr) {
        int m = m0 + rbase + rr * 32;
        int mm = (m < M) ? m : (M - 1);
        int im = mm / NPATCH;
        int p  = mm % NPATCH;
        int Pi = p / PGRID;
        int Pj = p % PGRID;
        arow[rr] = ((long)(im * CHN) * IMGW + Pi * PSZ) * IMGW + Pj * PSZ;
    }
    const int lane = tid & 63;
    const int wave = tid >> 6;
    const int wm = (wave & 1) * 64;
    const int wn = (wave >> 1) * 64;
    const int wq = lane >> 4;
    const int lr = lane & 15;
    f32x4 acc[4][4] = {};
    for (int k0 = 0; k0 < KDIM; k0 += 32) {
        {
            int k  = k0 + col4 * 4;
            int c  = k >> 8;
            int ph = (k >> 4) & 15;
            int pw = k & 15;
            long koff = (long)(c * IMGW + ph) * IMGW + pw;
            #pragma unroll
            for (int rr = 0; rr < 4; ++rr) {
                const float4 v = *(const float4*)(img + arow[rr] + koff);
                int row = rbase + rr * 32;
                short4 s;
                s.x = bf16rne(v.x); s.y = bf16rne(v.y);
                s.z = bf16rne(v.z); s.w = bf16rne(v.w);
                *(short4*)(&As[row * LDSTR + col4 * 4]) = s;
            }
        }
        {
            int k = k0 + col4 * 4;
            #pragma unroll
            for (int rr = 0; rr < 4; ++rr) {
                int nrow = rbase + rr * 32;
                const float4 v = *(const float4*)(Wl + (long)(n0 + nrow) * KDIM + k);
                short4 s;
                s.x = bf16rne(v.x); s.y = bf16rne(v.y);
                s.z = bf16rne(v.z); s.w = bf16rne(v.w);
                *(short4*)(&Bs[nrow * LDSTR + col4 * 4]) = s;
            }
        }
        __syncthreads();
        bf16x8 a[4], b[4];
        #pragma unroll
        for (int i = 0; i < 4; ++i)
            a[i] = *(const bf16x8*)(&As[(wm + i * 16 + lr) * LDSTR + wq * 8]);
        #pragma unroll
        for (int i = 0; i < 4; ++i)
            b[i] = *(const bf16x8*)(&Bs[(wn + i * 16 + lr) * LDSTR + wq * 8]);
        #pragma unroll
        for (int i = 0; i < 4; ++i)
            #pragma unroll
            for (int j = 0; j < 4; ++j)
                acc[i][j] = __builtin_amdgcn_mfma_f32_16x16x32_bf16(a[i], b[j], acc[i][j], 0, 0, 0);
        __syncthreads();
    }
    float bv[4];
    #pragma unroll
    for (int j = 0; j < 4; ++j) bv[j] = bias[n0 + wn + j * 16 + lr];
    #pragma unroll
    for (int i = 0; i < 4; ++i) {
        #pragma unroll
        for (int r = 0; r < 4; ++r) {
            int gm = m0 + wm + i * 16 + wq * 4 + r;
            if (gm < M) {
                int im = gm / NPATCH;
                int p  = gm % NPATCH;
                long orow = ((long)im * 197 + 1 + p) * (long)NDIM;
                #pragma unroll
                for (int j = 0; j < 4; ++j)
                    out[orow + n0 + wn + j * 16 + lr] = acc[i][j][r] + bv[j];
            }
        }
    }
}

__global__ __launch_bounds__(256) void cls_fill(
    const float* __restrict__ cls, float* __restrict__ out, int n_img)
{
    int i = blockIdx.x * 256 + threadIdx.x;
    if (i < n_img * NDIM) {
        int im = i / NDIM;
        int n  = i - im * NDIM;
        out[(long)im * 197 * NDIM + n] = cls[n];
    }
}

extern "C" void kernel_launch(void* const* d_in, const int* in_sizes, int n_in,
                              void* d_out, int out_size, void* d_ws, size_t ws_size,
                              hipStream_t stream) {
    const float* img  = (const float*)d_in[0];
    const float* Wl   = (const float*)d_in[1];
    const float* bias = (const float*)d_in[2];
    const float* cls  = (const float*)d_in[3];
    float* out = (float*)d_out;

    int n_img = in_sizes[0] / (CHN * IMGW * IMGW);
    int M = n_img * NPATCH;
    int mgroups = (M + 127) / 128;
    long Mpad = (long)mgroups * 128;

    size_t need = (size_t)(Mpad * KDIM + (long)KDIM * NDIM) * sizeof(short);
    if (ws_size >= need) {
        short* A_ws = (short*)d_ws;
        short* Wb   = A_ws + Mpad * KDIM;

        int total8 = n_img * (CHN * IMGW * IMGW / 8)
                   + KDIM * NDIM / 8
                   + n_img * (NDIM / 8);
        prep_all<<<(total8 + 255) / 256, 256, 0, stream>>>(img, Wl, cls, A_ws, Wb, out, n_img);

        // XCD-swizzled 1-D grid: pad m-groups to multiple of 8
        int gpad = (mgroups + 7) & ~7;
        int nblocks = gpad * 6;
        vit_gemm5<<<nblocks, 256, 0, stream>>>(A_ws, Wb, bias, out, M, mgroups);
    } else {
        dim3 grid(NDIM / 128, (M + 127) / 128);
        vit_gemm_fb<<<grid, 256, 0, stream>>>(img, Wl, bias, out, n_img);
        int cls_elems = n_img * NDIM;
        cls_fill<<<(cls_elems + 255) / 256, 256, 0, stream>>>(cls, out, n_img);
    }
}